// Round 4
// baseline (203.302 us; speedup 1.0000x reference)
//
#include <hip/hip_runtime.h>
#include <hip/hip_bf16.h>
#include <math.h>

// Problem dims (fixed by the reference): B=4096, M=2, D=2048
#define MROWS 8192   // B*M rows of the GEMM
#define KDIM  2048
#define NDIM  2048

#define BM 256
#define BN 256
#define BK 64
#define NT (KDIM / BK)   // 32 K-tiles

typedef short  v8s __attribute__((ext_vector_type(8)));   // 8 bf16 (4 VGPRs)
typedef float  v4f __attribute__((ext_vector_type(4)));   // MFMA acc

// workspace layout (bytes)
#define A_OFF   0ull
#define W_OFF   ((unsigned long long)MROWS * KDIM * 2ull)               // 32 MiB
#define MWZ_OFF (W_OFF + (unsigned long long)NDIM * KDIM * 2ull)        // +8 MiB

__device__ inline unsigned short f2bf(float f) {
    __hip_bfloat16 h = __float2bfloat16(f);   // RNE
    return *reinterpret_cast<unsigned short*>(&h);
}

// ---------------------------------------------------------------------------
// Prep: zeta scalar, A = bf16(x + emb[ids]), W = bf16(Wt)   [UNCHANGED]
// ---------------------------------------------------------------------------
__global__ __launch_bounds__(256) void prep_kernel(
    const float* __restrict__ x, const int* __restrict__ ids,
    const float* __restrict__ mw, const float* __restrict__ emb,
    const float* __restrict__ Wrc, const float* __restrict__ brc,
    const float* __restrict__ Wt,
    unsigned short* __restrict__ Abf, unsigned short* __restrict__ Wbf,
    float* __restrict__ mwz)
{
    const int tid = threadIdx.x;

    if (blockIdx.x == 0) {
        __shared__ float red[256];
        float s = 0.f;
        for (int d = tid; d < KDIM; d += 256) s += Wrc[d];
        red[tid] = s;
        __syncthreads();
        for (int off = 128; off > 0; off >>= 1) {
            if (tid < off) red[tid] += red[tid + off];
            __syncthreads();
        }
        if (tid == 0) {
            float zeta = 1.0f / (1.0f + expf(-(0.2f * red[0] + brc[0])));
            mwz[0] = mw[0] * zeta;
            mwz[1] = mw[1] * zeta;
        }
    }

    const int groupsA = MROWS * KDIM / 8;
    for (int g = blockIdx.x * 256 + tid; g < groupsA; g += gridDim.x * 256) {
        const int row = g >> 8;
        const int off = (g & 255) << 3;
        const int st  = ids[row];
        const float4* xp = (const float4*)(x   + (size_t)row * KDIM + off);
        const float4* ep = (const float4*)(emb + (size_t)st  * KDIM + off);
        float4 x0 = xp[0], x1 = xp[1];
        float4 e0 = ep[0], e1 = ep[1];
        v8s o;
        o[0] = (short)f2bf(x0.x + e0.x);
        o[1] = (short)f2bf(x0.y + e0.y);
        o[2] = (short)f2bf(x0.z + e0.z);
        o[3] = (short)f2bf(x0.w + e0.w);
        o[4] = (short)f2bf(x1.x + e1.x);
        o[5] = (short)f2bf(x1.y + e1.y);
        o[6] = (short)f2bf(x1.z + e1.z);
        o[7] = (short)f2bf(x1.w + e1.w);
        *(v8s*)(Abf + (size_t)g * 8) = o;
    }

    const int groupsW = NDIM * KDIM / 8;
    for (int g = blockIdx.x * 256 + tid; g < groupsW; g += gridDim.x * 256) {
        const float4* wp = (const float4*)(Wt + (size_t)g * 8);
        float4 w0 = wp[0], w1 = wp[1];
        v8s o;
        o[0] = (short)f2bf(w0.x); o[1] = (short)f2bf(w0.y);
        o[2] = (short)f2bf(w0.z); o[3] = (short)f2bf(w0.w);
        o[4] = (short)f2bf(w1.x); o[5] = (short)f2bf(w1.y);
        o[6] = (short)f2bf(w1.z); o[7] = (short)f2bf(w1.w);
        *(v8s*)(Wbf + (size_t)g * 8) = o;
    }
}

// ---------------------------------------------------------------------------
// GEMM v5: T3-minimum 2-phase schedule (catalog recipe), 256x256, 8 waves,
// BK=64, static LDS double-buffers. Per K-tile:
//   1. issue 8 global_load_lds for tile t+1 into the OTHER buffers
//   2. 24 ds_read_b128 + 64 MFMA from CURRENT buffers (compiler-scheduled,
//      fine-grained lgkmcnt; setprio(1) around each 16-MFMA cluster)
//   3. lgkmcnt(0)  — my reads landed (region safe to overwrite after barrier)
//      vmcnt(0)    — my stage DMAs landed (tile t+1 complete after barrier)
//      s_barrier   — single sync point per K-tile
//
// Why this replaces v4's 4-phase/8-barrier schedule: v4 measured 75.7 us /
// MfmaUtil 36% (5700 cyc/K-tile vs 2048 ideal). Its counted cross-barrier
// vmcnt scheme fights SIInsertWaitcnts, which cannot parse inline-asm waits
// and re-inserts its own waits at every same-object DMA-vs-ds_read site;
// with only ~512 cyc of MFMA per phase, 8 barriers + redundant waits
// dominate. Here the stage is issued BEFORE ~2048 cyc of compute (unlike
// the R0 2-barrier kernel, which drained immediately after staging — its
// documented ~20% stall), so the single vmcnt(0) catches only the tail,
// and any compiler-auto-inserted wait before the reads is counted (~vmcnt(8))
// and already satisfied. Cross-wave safety = R0's proven pattern: every wave
// drains its own DMA + reads before the barrier.
//
// Kept from v4 (all counter-verified): static dbuf objects (lA0/lA1/lB0/lB1),
// fetch-side XOR swizzle (SQ_LDS_BANK_CONFLICT = 0), fragment unswizzle math,
// R3 2D block mapping (FETCH_SIZE compulsory-only 52 GB-units), operand-swap
// epilogue with dwordx4 stores.
// ---------------------------------------------------------------------------

#define SBAR()   __builtin_amdgcn_s_barrier()
#define LGKM0()  asm volatile("s_waitcnt lgkmcnt(0)" ::: "memory")
#define VMCNT(n) asm volatile("s_waitcnt vmcnt(" #n ")" ::: "memory")

template<int P>
__device__ __forceinline__ void mfma_phase(v4f (&acc)[8][4],
                                           const v8s (&b)[4][2],
                                           const v8s (&a)[2][2])
{
    __builtin_amdgcn_s_setprio(1);
    #pragma unroll
    for (int j = 0; j < 4; ++j) {
        acc[2*P  ][j] = __builtin_amdgcn_mfma_f32_16x16x32_bf16(b[j][0], a[0][0], acc[2*P  ][j], 0, 0, 0);
        acc[2*P+1][j] = __builtin_amdgcn_mfma_f32_16x16x32_bf16(b[j][0], a[1][0], acc[2*P+1][j], 0, 0, 0);
    }
    #pragma unroll
    for (int j = 0; j < 4; ++j) {
        acc[2*P  ][j] = __builtin_amdgcn_mfma_f32_16x16x32_bf16(b[j][1], a[0][1], acc[2*P  ][j], 0, 0, 0);
        acc[2*P+1][j] = __builtin_amdgcn_mfma_f32_16x16x32_bf16(b[j][1], a[1][1], acc[2*P+1][j], 0, 0, 0);
    }
    __builtin_amdgcn_s_setprio(0);
}

// One K-tile: stage t+1 into (NA,NB), compute tile T from (CA,CB), then
// lgkm0 + vmcnt0 + barrier. All buffer names are static array identifiers.
#define KTILE2(CA, CB, NA, NB, T)                                         \
  {                                                                       \
    if ((T) + 1 < NT) {                                                   \
      stage(NB, gB, (T) + 1, 0); stage(NB, gB, (T) + 1, 1);               \
      stage(NB, gB, (T) + 1, 2); stage(NB, gB, (T) + 1, 3);               \
      stage(NA, gA, (T) + 1, 0); stage(NA, gA, (T) + 1, 1);               \
      stage(NA, gA, (T) + 1, 2); stage(NA, gA, (T) + 1, 3);               \
    }                                                                     \
    v8s a[2][2], b[4][2];                                                 \
    b[0][0] = rdB(CB, 0, 0); b[0][1] = rdB(CB, 0, 1);                     \
    b[1][0] = rdB(CB, 1, 0); b[1][1] = rdB(CB, 1, 1);                     \
    b[2][0] = rdB(CB, 2, 0); b[2][1] = rdB(CB, 2, 1);                     \
    b[3][0] = rdB(CB, 3, 0); b[3][1] = rdB(CB, 3, 1);                     \
    a[0][0] = rdA(CA, 0, 0); a[0][1] = rdA(CA, 0, 1);                     \
    a[1][0] = rdA(CA, 1, 0); a[1][1] = rdA(CA, 1, 1);                     \
    mfma_phase<0>(acc, b, a);                                             \
    a[0][0] = rdA(CA, 2, 0); a[0][1] = rdA(CA, 2, 1);                     \
    a[1][0] = rdA(CA, 3, 0); a[1][1] = rdA(CA, 3, 1);                     \
    mfma_phase<1>(acc, b, a);                                             \
    a[0][0] = rdA(CA, 4, 0); a[0][1] = rdA(CA, 4, 1);                     \
    a[1][0] = rdA(CA, 5, 0); a[1][1] = rdA(CA, 5, 1);                     \
    mfma_phase<2>(acc, b, a);                                             \
    a[0][0] = rdA(CA, 6, 0); a[0][1] = rdA(CA, 6, 1);                     \
    a[1][0] = rdA(CA, 7, 0); a[1][1] = rdA(CA, 7, 1);                     \
    mfma_phase<3>(acc, b, a);                                             \
    LGKM0(); VMCNT(0); SBAR();                                            \
  }

__global__ __launch_bounds__(512, 2) void gemm_kernel(
    const unsigned short* __restrict__ Abf,
    const unsigned short* __restrict__ Wbf,
    const float* __restrict__ bt,
    const float* __restrict__ mwz,
    float* __restrict__ out)
{
    // STATIC double-buffers: four distinct LDS objects.
    __shared__ __align__(16) unsigned short lA0[BM * BK];   // 32 KiB
    __shared__ __align__(16) unsigned short lA1[BM * BK];   // 32 KiB
    __shared__ __align__(16) unsigned short lB0[BN * BK];   // 32 KiB
    __shared__ __align__(16) unsigned short lB1[BN * BK];   // 32 KiB

    const int tid  = threadIdx.x;
    const int lane = tid & 63;
    const int wave = tid >> 6;        // 0..7
    const int wr   = wave & 1;        // M half (128 rows)
    const int wc   = wave >> 1;       // N quarter (64 cols)
    const int quad = lane >> 4;       // 0..3
    const int mcol = lane & 15;       // 0..15

    // R3-proven mapping: br fast in blockIdx.x, bc in blockIdx.y.
    const int br = blockIdx.x;        // 32 row-blocks
    const int bc = blockIdx.y;        // 8 col-blocks

    const unsigned short* gA = Abf + (size_t)(br * BM) * KDIM;
    const unsigned short* gB = Wbf + (size_t)(bc * BN) * KDIM;

    v4f acc[8][4];
    const v4f vzero = {0.f, 0.f, 0.f, 0.f};
    #pragma unroll
    for (int i = 0; i < 8; i++)
        #pragma unroll
        for (int j = 0; j < 4; j++) acc[i][j] = vzero;

    // --- stage one 64-row quarter (8 KiB = 512 thr x 16 B) of a tile ---
    // LDS slot f holds row=f>>3, global chunk ch=(f&7)^(row&7)  (verified T2)
    auto stage = [&](unsigned short* dst, const unsigned short* gsrc,
                     int t, int s) {
        const int f   = (s << 9) + tid;
        const int row = f >> 3;
        const int ch  = (f & 7) ^ (row & 7);
        const unsigned short* g = gsrc + (size_t)row * KDIM + ((t & 31) << 6) + (ch << 3);
        __builtin_amdgcn_global_load_lds(
            (const __attribute__((address_space(1))) void*)g,
            (__attribute__((address_space(3))) void*)(dst + ((size_t)f << 3)),
            16, 0, 0);
    };

    // --- fragment reads (identical unswizzle math to verified R3 kernel) ---
    auto rdA = [&](const unsigned short* l, int i, int ks) -> v8s {
        const int row = (wr << 7) + (i << 4) + mcol;
        const int c   = ((ks << 2) + quad) ^ (row & 7);
        return *(const v8s*)(l + (row << 6) + (c << 3));
    };
    auto rdB = [&](const unsigned short* l, int j, int ks) -> v8s {
        const int col = (wc << 6) + (j << 4) + mcol;
        const int c   = ((ks << 2) + quad) ^ (col & 7);
        return *(const v8s*)(l + (col << 6) + (c << 3));
    };

    // ---- prologue: stage tile 0, drain, sync ----
    stage(lB0, gB, 0, 0); stage(lB0, gB, 0, 1);
    stage(lB0, gB, 0, 2); stage(lB0, gB, 0, 3);
    stage(lA0, gA, 0, 0); stage(lA0, gA, 0, 1);
    stage(lA0, gA, 0, 2); stage(lA0, gA, 0, 3);
    VMCNT(0);
    SBAR();

    #pragma unroll 1
    for (int tt = 0; tt < NT; tt += 2) {
        KTILE2(lA0, lB0, lA1, lB1, tt);       // even tile: compute bufs 0
        KTILE2(lA1, lB1, lA0, lB0, tt + 1);   // odd tile:  compute bufs 1
    }

    // ---- epilogue: bias + relu + scale + relu, dwordx4 fp32 stores ----
    // operand swap => acc holds out^T tile: reg-index = output COLUMN,
    // mcol = output ROW. Row parity = mcol & 1 (all tile offsets even).
    const float mz = mwz[mcol & 1];
    #pragma unroll
    for (int j = 0; j < 4; ++j) {
        const int ncol = bc * BN + wc * 64 + j * 16 + quad * 4;
        const float4 b4 = *(const float4*)(bt + ncol);
        #pragma unroll
        for (int i = 0; i < 8; ++i) {
            const int row = br * BM + wr * 128 + i * 16 + mcol;
            float4 o;
            o.x = fmaxf(mz * fmaxf(acc[i][j][0] + b4.x, 0.0f), 0.0f);
            o.y = fmaxf(mz * fmaxf(acc[i][j][1] + b4.y, 0.0f), 0.0f);
            o.z = fmaxf(mz * fmaxf(acc[i][j][2] + b4.z, 0.0f), 0.0f);
            o.w = fmaxf(mz * fmaxf(acc[i][j][3] + b4.w, 0.0f), 0.0f);
            *(float4*)(out + (size_t)row * NDIM + ncol) = o;
        }
    }
}

// ---------------------------------------------------------------------------
extern "C" void kernel_launch(void* const* d_in, const int* in_sizes, int n_in,
                              void* d_out, int out_size, void* d_ws, size_t ws_size,
                              hipStream_t stream) {
    const float* x    = (const float*)d_in[0];
    const int*   ids  = (const int*)  d_in[1];
    const float* mw   = (const float*)d_in[2];
    const float* emb  = (const float*)d_in[3];
    const float* Wt   = (const float*)d_in[4];
    const float* bt   = (const float*)d_in[5];
    const float* Wrc  = (const float*)d_in[6];
    const float* brc  = (const float*)d_in[7];
    float* out = (float*)d_out;

    char* ws = (char*)d_ws;
    unsigned short* Abf = (unsigned short*)(ws + A_OFF);
    unsigned short* Wbf = (unsigned short*)(ws + W_OFF);
    float* mwz          = (float*)(ws + MWZ_OFF);

    prep_kernel<<<2048, 256, 0, stream>>>(x, ids, mw, emb, Wrc, brc, Wt,
                                          Abf, Wbf, mwz);

    dim3 grid(MROWS / BM, NDIM / BN);   // 32 x 8 = 256 blocks = 1/CU exactly
    gemm_kernel<<<grid, 512, 0, stream>>>(Abf, Wbf, bt, mwz, out);
}